// Round 2
// baseline (231.352 us; speedup 1.0000x reference)
//
#include <hip/hip_runtime.h>

// Problem constants (from reference): N=1e6, D1=D2=16, NC=64 outer, NCPC=8 inner.
constexpr int D = 16;
constexpr int NC = 64;
constexpr int NCPC = 8;
constexpr int OSTRIDE = NCPC * D + 4;   // 132 floats: pad 4 so start bank = (4*o)%32, 16B aligned
constexpr int NPT = 2;                  // points per thread
constexpr int BLOCK = 512;              // 512 thr/block: 4 blocks/CU (LDS) = 2048 thr/CU = 8 waves/SIMD

__global__ __launch_bounds__(BLOCK, 8)  // 8 waves/EU -> VGPR cap 64; LDS 36.3KB*4 = 145KB <= 160KB
void cluster_kernel(const float* __restrict__ x,
                    const float* __restrict__ co,
                    const float* __restrict__ ci,
                    int* __restrict__ out, int n)
{
    // Inner-center table + norms in LDS. 64*132*4 + 64*4 + 576*4 = 36352 B.
    __shared__ __align__(16) float s_ci[NC * OSTRIDE];
    __shared__ __align__(16) float s_onorm[NC];
    __shared__ float s_inorm[NC * 9];            // [o][k], stride 9 to spread banks

    const int t = threadIdx.x;

    // ---- Block setup: stage inner centers (8192 floats = 2048 float4) into LDS ----
    const float4* ci4 = (const float4*)ci;
    #pragma unroll
    for (int i = 0; i < (NC * NCPC * D / 4) / BLOCK; ++i) {   // 4 iters at BLOCK=512
        int idx = t + i * BLOCK;        // 0..2047
        int o = idx >> 5;               // 32 float4 per outer cluster
        int f = idx & 31;               // k*4 + d4
        float4 v = ci4[idx];
        *(float4*)&s_ci[o * OSTRIDE + f * 4] = v;
    }
    // ---- 576 norms (64 outer + 512 inner), ~1-2 per thread, once per block ----
    for (int i = t; i < NC + NC * NCPC; i += BLOCK) {
        const float* src = (i < NC) ? (co + i * D) : (ci + (i - NC) * D);
        float s = 0.f;
        #pragma unroll
        for (int k = 0; k < D; ++k) s = fmaf(src[k], src[k], s);
        if (i < NC) {
            s_onorm[i] = s;
        } else {
            int ii = i - NC;
            s_inorm[(ii >> 3) * 9 + (ii & 7)] = s;
        }
    }
    __syncthreads();

    const int base = blockIdx.x * (BLOCK * NPT) + t;
    #pragma unroll 1                       // keep body in I-cache
    for (int it = 0; it < NPT; ++it) {
        int p = base + it * BLOCK;
        if (p < n) {
            const float4* xp = (const float4*)(x + (size_t)p * 32);
            // Load only x1 now; x2 loads deferred past the outer argmin so the
            // two 16-float arrays are never simultaneously live (VGPR <= 64).
            float4 xa = xp[0], xb = xp[1], xc = xp[2], xd = xp[3];
            float x1[16] = {xa.x,xa.y,xa.z,xa.w, xb.x,xb.y,xb.z,xb.w,
                            xc.x,xc.y,xc.z,xc.w, xd.x,xd.y,xd.z,xd.w};

            // ---- Outer argmin: d = ||c_j||^2 - 2 x1.c_j ; centers via wave-uniform
            //      global access -> s_load_dwordx16 (constant cache), zero VMEM cost ----
            float bestd = 3.4e38f;
            int bo = 0;
            #pragma unroll
            for (int jt = 0; jt < NC / 4; ++jt) {
                float4 nn = *(const float4*)&s_onorm[jt * 4];   // broadcast ds_read_b128
                #pragma unroll
                for (int jj = 0; jj < 4; ++jj) {
                    int j = jt * 4 + jj;
                    const float* c = co + j * D;
                    float dot = 0.f;
                    #pragma unroll
                    for (int k = 0; k < D; ++k) dot = fmaf(x1[k], c[k], dot);
                    float nrm = (jj == 0) ? nn.x : (jj == 1) ? nn.y : (jj == 2) ? nn.z : nn.w;
                    float d = fmaf(-2.f, dot, nrm);
                    if (d < bestd) { bestd = d; bo = j; }   // strict < : first index wins (np.argmin)
                }
            }

            // ---- Now load x2 (x1 registers dead -> reusable) ----
            float4 ya = xp[4], yb = xp[5], yc = xp[6], yd = xp[7];
            float x2[16] = {ya.x,ya.y,ya.z,ya.w, yb.x,yb.y,yb.z,yb.w,
                            yc.x,yc.y,yc.z,yc.w, yd.x,yd.y,yd.z,yd.w};

            // ---- Inner argmin over the 8 sub-centers of bo (LDS gather) ----
            const float* cb = s_ci + bo * OSTRIDE;
            const float* nb = s_inorm + bo * 9;
            float bestd2 = 3.4e38f;
            int bk = 0;
            #pragma unroll
            for (int k = 0; k < NCPC; ++k) {
                float4 c0 = *(const float4*)&cb[k * D + 0];
                float4 c1 = *(const float4*)&cb[k * D + 4];
                float4 c2 = *(const float4*)&cb[k * D + 8];
                float4 c3 = *(const float4*)&cb[k * D + 12];
                float dot = 0.f;
                dot = fmaf(x2[0],  c0.x, dot); dot = fmaf(x2[1],  c0.y, dot);
                dot = fmaf(x2[2],  c0.z, dot); dot = fmaf(x2[3],  c0.w, dot);
                dot = fmaf(x2[4],  c1.x, dot); dot = fmaf(x2[5],  c1.y, dot);
                dot = fmaf(x2[6],  c1.z, dot); dot = fmaf(x2[7],  c1.w, dot);
                dot = fmaf(x2[8],  c2.x, dot); dot = fmaf(x2[9],  c2.y, dot);
                dot = fmaf(x2[10], c2.z, dot); dot = fmaf(x2[11], c2.w, dot);
                dot = fmaf(x2[12], c3.x, dot); dot = fmaf(x2[13], c3.y, dot);
                dot = fmaf(x2[14], c3.z, dot); dot = fmaf(x2[15], c3.w, dot);
                float d = fmaf(-2.f, dot, nb[k]);
                if (d < bestd2) { bestd2 = d; bk = k; }
            }

            out[p] = bo * NCPC + bk;
        }
    }
}

extern "C" void kernel_launch(void* const* d_in, const int* in_sizes, int n_in,
                              void* d_out, int out_size, void* d_ws, size_t ws_size,
                              hipStream_t stream) {
    const float* x  = (const float*)d_in[0];   // (N, 32) fp32
    const float* co = (const float*)d_in[1];   // (64, 16) fp32
    const float* ci = (const float*)d_in[2];   // (64, 8, 16) fp32
    int* out = (int*)d_out;                    // (N,) int32
    int n = in_sizes[0] / 32;
    int blocks = (n + BLOCK * NPT - 1) / (BLOCK * NPT);
    cluster_kernel<<<blocks, BLOCK, 0, stream>>>(x, co, ci, out, n);
}

// Round 3
// 195.753 us; speedup vs baseline: 1.1819x; 1.1819x over previous
//
#include <hip/hip_runtime.h>

// Problem constants (from reference): N=1e6, D1=D2=16, NC=64 outer, NCPC=8 inner.
constexpr int D = 16;
constexpr int NC = 64;
constexpr int NCPC = 8;
constexpr int OSTRIDE = NCPC * D + 4;   // 132 floats: pad 4 so start bank = (4*o)%32, 16B aligned
constexpr int NPT = 2;                  // points per thread
constexpr int BLOCK = 512;              // 512 thr/block: 4 blocks/CU (LDS) = 2048 thr/CU = 8 waves/SIMD

// NOTE (R2 post-mortem): __launch_bounds__(512, 8) produced VGPR_Count=32 + ~170MB
// scratch spill traffic -> 2nd arg behaves as min BLOCKS/CU (CUDA semantics) on this
// toolchain: 8 blocks*512thr = 64 waves/CU -> 2048/64 = 32 VGPRs. With 4: 4 blocks/CU
// = 32 waves/CU -> 64-VGPR cap, which the ~50-reg live set fits without spilling.
__global__ __launch_bounds__(BLOCK, 4)
void cluster_kernel(const float* __restrict__ x,
                    const float* __restrict__ co,
                    const float* __restrict__ ci,
                    int* __restrict__ out, int n)
{
    // Inner-center table + norms in LDS. 64*132*4 + 64*4 + 576*4 = 36352 B.
    __shared__ __align__(16) float s_ci[NC * OSTRIDE];
    __shared__ __align__(16) float s_onorm[NC];
    __shared__ float s_inorm[NC * 9];            // [o][k], stride 9 to spread banks

    const int t = threadIdx.x;

    // ---- Block setup: stage inner centers (8192 floats = 2048 float4) into LDS ----
    const float4* ci4 = (const float4*)ci;
    #pragma unroll
    for (int i = 0; i < (NC * NCPC * D / 4) / BLOCK; ++i) {   // 4 iters at BLOCK=512
        int idx = t + i * BLOCK;        // 0..2047
        int o = idx >> 5;               // 32 float4 per outer cluster
        int f = idx & 31;               // k*4 + d4
        float4 v = ci4[idx];
        *(float4*)&s_ci[o * OSTRIDE + f * 4] = v;
    }
    // ---- 576 norms (64 outer + 512 inner), ~1-2 per thread, once per block ----
    for (int i = t; i < NC + NC * NCPC; i += BLOCK) {
        const float* src = (i < NC) ? (co + i * D) : (ci + (i - NC) * D);
        float s = 0.f;
        #pragma unroll
        for (int k = 0; k < D; ++k) s = fmaf(src[k], src[k], s);
        if (i < NC) {
            s_onorm[i] = s;
        } else {
            int ii = i - NC;
            s_inorm[(ii >> 3) * 9 + (ii & 7)] = s;
        }
    }
    __syncthreads();

    const int base = blockIdx.x * (BLOCK * NPT) + t;
    #pragma unroll 1                       // keep body in I-cache
    for (int it = 0; it < NPT; ++it) {
        int p = base + it * BLOCK;
        if (p < n) {
            const float4* xp = (const float4*)(x + (size_t)p * 32);
            // Load only x1 now; x2 loads deferred past the outer argmin so the
            // two 16-float arrays are never simultaneously live (VGPR <= 64).
            float4 xa = xp[0], xb = xp[1], xc = xp[2], xd = xp[3];
            float x1[16] = {xa.x,xa.y,xa.z,xa.w, xb.x,xb.y,xb.z,xb.w,
                            xc.x,xc.y,xc.z,xc.w, xd.x,xd.y,xd.z,xd.w};

            // ---- Outer argmin: d = ||c_j||^2 - 2 x1.c_j ; centers via wave-uniform
            //      global access -> s_load_dwordx16 (constant cache), zero VMEM cost ----
            float bestd = 3.4e38f;
            int bo = 0;
            #pragma unroll
            for (int jt = 0; jt < NC / 4; ++jt) {
                float4 nn = *(const float4*)&s_onorm[jt * 4];   // broadcast ds_read_b128
                #pragma unroll
                for (int jj = 0; jj < 4; ++jj) {
                    int j = jt * 4 + jj;
                    const float* c = co + j * D;
                    float dot = 0.f;
                    #pragma unroll
                    for (int k = 0; k < D; ++k) dot = fmaf(x1[k], c[k], dot);
                    float nrm = (jj == 0) ? nn.x : (jj == 1) ? nn.y : (jj == 2) ? nn.z : nn.w;
                    float d = fmaf(-2.f, dot, nrm);
                    if (d < bestd) { bestd = d; bo = j; }   // strict < : first index wins (np.argmin)
                }
            }

            // ---- Now load x2 (x1 registers dead -> reusable) ----
            float4 ya = xp[4], yb = xp[5], yc = xp[6], yd = xp[7];
            float x2[16] = {ya.x,ya.y,ya.z,ya.w, yb.x,yb.y,yb.z,yb.w,
                            yc.x,yc.y,yc.z,yc.w, yd.x,yd.y,yd.z,yd.w};

            // ---- Inner argmin over the 8 sub-centers of bo (LDS gather) ----
            const float* cb = s_ci + bo * OSTRIDE;
            const float* nb = s_inorm + bo * 9;
            float bestd2 = 3.4e38f;
            int bk = 0;
            #pragma unroll
            for (int k = 0; k < NCPC; ++k) {
                float4 c0 = *(const float4*)&cb[k * D + 0];
                float4 c1 = *(const float4*)&cb[k * D + 4];
                float4 c2 = *(const float4*)&cb[k * D + 8];
                float4 c3 = *(const float4*)&cb[k * D + 12];
                float dot = 0.f;
                dot = fmaf(x2[0],  c0.x, dot); dot = fmaf(x2[1],  c0.y, dot);
                dot = fmaf(x2[2],  c0.z, dot); dot = fmaf(x2[3],  c0.w, dot);
                dot = fmaf(x2[4],  c1.x, dot); dot = fmaf(x2[5],  c1.y, dot);
                dot = fmaf(x2[6],  c1.z, dot); dot = fmaf(x2[7],  c1.w, dot);
                dot = fmaf(x2[8],  c2.x, dot); dot = fmaf(x2[9],  c2.y, dot);
                dot = fmaf(x2[10], c2.z, dot); dot = fmaf(x2[11], c2.w, dot);
                dot = fmaf(x2[12], c3.x, dot); dot = fmaf(x2[13], c3.y, dot);
                dot = fmaf(x2[14], c3.z, dot); dot = fmaf(x2[15], c3.w, dot);
                float d = fmaf(-2.f, dot, nb[k]);
                if (d < bestd2) { bestd2 = d; bk = k; }
            }

            out[p] = bo * NCPC + bk;
        }
    }
}

extern "C" void kernel_launch(void* const* d_in, const int* in_sizes, int n_in,
                              void* d_out, int out_size, void* d_ws, size_t ws_size,
                              hipStream_t stream) {
    const float* x  = (const float*)d_in[0];   // (N, 32) fp32
    const float* co = (const float*)d_in[1];   // (64, 16) fp32
    const float* ci = (const float*)d_in[2];   // (64, 8, 16) fp32
    int* out = (int*)d_out;                    // (N,) int32
    int n = in_sizes[0] / 32;
    int blocks = (n + BLOCK * NPT - 1) / (BLOCK * NPT);
    cluster_kernel<<<blocks, BLOCK, 0, stream>>>(x, co, ci, out, n);
}